// Round 1
// baseline (1211.396 us; speedup 1.0000x reference)
//
#include <hip/hip_runtime.h>

#define Bc 8
#define Td 4096
#define Hd 1024
#define N3 3072
#define Md (Bc*Td)      // 32768
#define Kd Hd           // 1024

#define BM 128
#define BN 128
#define BK 64
#define NC 64           // chunks along T
#define CL (Td/NC)      // 64 steps per chunk

typedef _Float16 half8 __attribute__((ext_vector_type(8)));
typedef _Float16 half4v __attribute__((ext_vector_type(4)));
typedef float floatx4 __attribute__((ext_vector_type(4)));

typedef __attribute__((address_space(3))) unsigned int lds_u32;
typedef __attribute__((address_space(1))) const unsigned int glob_u32;

__device__ __forceinline__ void async_lds16(const void* g, void* l) {
    __builtin_amdgcn_global_load_lds((glob_u32*)g, (lds_u32*)l, 16, 0, 0);
}

// ---------------- fp32 -> fp16 convert (vectorized x4) ----------------
__global__ void cvt16(const float4* __restrict__ x, half4v* __restrict__ y, int n4) {
    int i = blockIdx.x * blockDim.x + threadIdx.x;
    if (i < n4) {
        float4 v = x[i];
        half4v o;
        o[0] = (_Float16)v.x; o[1] = (_Float16)v.y;
        o[2] = (_Float16)v.z; o[3] = (_Float16)v.w;
        y[i] = o;
    }
}

// ---------------- W [K,N] fp32 -> Wt [N,K] fp16 (LDS-tiled transpose) --
__global__ void wtrans(const float* __restrict__ W, _Float16* __restrict__ Wt) {
    __shared__ float t[32][33];
    int n0 = blockIdx.x * 32, k0 = blockIdx.y * 32;
    int tx = threadIdx.x, ty = threadIdx.y;
    t[ty][tx] = W[(size_t)(k0 + ty) * N3 + n0 + tx];
    __syncthreads();
    Wt[(size_t)(n0 + ty) * Kd + k0 + tx] = (_Float16)t[tx][ty];
}

// ---------------- GEMM: C[M,N] = A[M,K] * Bt[N,K]^T, fp16 in, fp16 out -
__global__ __launch_bounds__(256) void gemm_f16_bt(
    const _Float16* __restrict__ A,   // [M,K]
    const _Float16* __restrict__ Bt,  // [N,K]
    _Float16* __restrict__ C)         // [M,N]
{
    __shared__ _Float16 As[BM * BK];
    __shared__ _Float16 Bs[BN * BK];
    const int tid  = threadIdx.x;
    const int wave = tid >> 6;
    const int lane = tid & 63;
    const int bm = blockIdx.y * BM;
    const int bn = blockIdx.x * BN;
    const int wm = (wave >> 1) * 64;
    const int wn = (wave & 1) * 64;
    const int quad = lane >> 4;
    const int lr   = lane & 15;

    floatx4 acc[4][4];
#pragma unroll
    for (int i = 0; i < 4; ++i)
#pragma unroll
        for (int j = 0; j < 4; ++j) { floatx4 z = {0.f,0.f,0.f,0.f}; acc[i][j] = z; }

    const int e0 = wave * 2048 + lane * 8;   // element index base for staging

    for (int k0 = 0; k0 < Kd; k0 += BK) {
        // stage A and B tiles: 4 rounds each, wave-uniform LDS base + lane*16
#pragma unroll
        for (int r = 0; r < 4; ++r) {
            int e = e0 + r * 512;
            int m = e >> 6;      // row in tile
            int k = e & 63;
            const _Float16* ga = A  + (size_t)(bm + m) * Kd + (k0 + k);
            const _Float16* gb = Bt + (size_t)(bn + m) * Kd + (k0 + k);
            char* la = (char*)As + (wave * 4 + r) * 1024;
            char* lb = (char*)Bs + (wave * 4 + r) * 1024;
            async_lds16(ga, la);
            async_lds16(gb, lb);
        }
        __syncthreads();
#pragma unroll
        for (int kk = 0; kk < BK; kk += 32) {
            half8 af[4], bf[4];
#pragma unroll
            for (int i = 0; i < 4; ++i)
                af[i] = *(const half8*)&As[(wm + i * 16 + lr) * BK + kk + quad * 8];
#pragma unroll
            for (int j = 0; j < 4; ++j)
                bf[j] = *(const half8*)&Bs[(wn + j * 16 + lr) * BK + kk + quad * 8];
#pragma unroll
            for (int i = 0; i < 4; ++i)
#pragma unroll
                for (int j = 0; j < 4; ++j)
                    acc[i][j] = __builtin_amdgcn_mfma_f32_16x16x32_f16(af[i], bf[j], acc[i][j], 0, 0, 0);
        }
        __syncthreads();
    }

    // epilogue: C/D layout col = lane&15, row = quad*4 + reg  [m89-verified]
#pragma unroll
    for (int i = 0; i < 4; ++i) {
#pragma unroll
        for (int j = 0; j < 4; ++j) {
            int row0 = bm + wm + i * 16 + quad * 4;
            int col  = bn + wn + j * 16 + lr;
#pragma unroll
            for (int r = 0; r < 4; ++r)
                C[(size_t)(row0 + r) * N3 + col] = (_Float16)acc[i][j][r];
        }
    }
}

// ---------------- scan phase 1: per-chunk (A, B) composition ----------
__global__ __launch_bounds__(256) void scan_phase1(
    const _Float16* __restrict__ Z, float* __restrict__ cA, float* __restrict__ cB)
{
    int ch = blockIdx.x * 256 + threadIdx.x;   // 0..1023 (gridDim.x = 4)
    int c  = blockIdx.y;
    int b  = blockIdx.z;
    int t0 = c * CL;
    float Ap = 1.0f, Bv = 0.0f;
    const _Float16* zp = Z + ((size_t)(b * Td + t0)) * N3 + ch;
#pragma unroll 4
    for (int t = 0; t < CL; ++t) {
        float hv = (float)zp[0];
        float gv = (float)zp[Hd];
        float sg = 1.0f / (1.0f + __expf(-gv));       // sigmoid(gate)
        float at = 1.0f / (1.0f + __expf(gv));        // 1 - sigmoid(gate)
        float gh = (hv >= 0.0f) ? (hv + 0.5f) : 1.0f / (1.0f + __expf(-hv));
        float bt = sg * gh;
        Ap *= at;
        Bv = fmaf(at, Bv, bt);
        zp += N3;
    }
    size_t o = ((size_t)b * NC + c) * Hd + ch;
    cA[o] = Ap; cB[o] = Bv;
}

// ---------------- scan phase 2: prefix over chunks --------------------
__global__ void scan_phase2(const float* __restrict__ cA, const float* __restrict__ cB,
                            float* __restrict__ cS)
{
    int u = blockIdx.x * 256 + threadIdx.x;    // B*H = 8192 threads
    int b = u >> 10, ch = u & 1023;
    float s = 0.0f;
    for (int c = 0; c < NC; ++c) {
        size_t o = ((size_t)b * NC + c) * Hd + ch;
        cS[o] = s;
        s = fmaf(cA[o], s, cB[o]);
    }
}

// ---------------- scan phase 3: rescan + highway gate + fp16 out ------
__global__ __launch_bounds__(256) void scan_phase3(
    const _Float16* __restrict__ Z, const float* __restrict__ cS,
    const float* __restrict__ hin, float* __restrict__ hout,
    _Float16* __restrict__ hout16)
{
    int ch = blockIdx.x * 256 + threadIdx.x;
    int c  = blockIdx.y;
    int b  = blockIdx.z;
    int t0 = c * CL;
    float s = cS[((size_t)b * NC + c) * Hd + ch];
    const _Float16* zp = Z + ((size_t)(b * Td + t0)) * N3 + ch;
    size_t ho = ((size_t)(b * Td + t0)) * Hd + ch;
#pragma unroll 2
    for (int t = 0; t < CL; ++t) {
        float hv = (float)zp[0];
        float gv = (float)zp[Hd];
        float pv = (float)zp[2 * Hd];
        float sg = 1.0f / (1.0f + __expf(-gv));
        float at = 1.0f / (1.0f + __expf(gv));
        float gh = (hv >= 0.0f) ? (hv + 0.5f) : 1.0f / (1.0f + __expf(-hv));
        s = fmaf(at, s, sg * gh);
        float gg = 1.0f / (1.0f + __expf(-pv));
        float hi = hin[ho];
        float o  = fmaf(gg, s - hi, hi);
        hout[ho] = o;
        if (hout16) hout16[ho] = (_Float16)o;
        zp += N3; ho += Hd;
    }
}

extern "C" void kernel_launch(void* const* d_in, const int* in_sizes, int n_in,
                              void* d_out, int out_size, void* d_ws, size_t ws_size,
                              hipStream_t stream) {
    const float* h  = (const float*)d_in[0];
    const float* W0 = (const float*)d_in[1];
    const float* W1 = (const float*)d_in[2];
    float* out = (float*)d_out;

    char* ws = (char*)d_ws;
    _Float16* Z    = (_Float16*)ws; ws += (size_t)Md * N3 * 2;     // 201 MB
    _Float16* Hbf  = (_Float16*)ws; ws += (size_t)Md * Kd * 2;     // 67 MB
    _Float16* Wt   = (_Float16*)ws; ws += (size_t)N3 * Kd * 2;     // 6 MB
    float* cA   = (float*)ws; ws += (size_t)Bc * NC * Hd * 4;      // 2 MB
    float* cB   = (float*)ws; ws += (size_t)Bc * NC * Hd * 4;
    float* cS   = (float*)ws; ws += (size_t)Bc * NC * Hd * 4;
    float* hmid = (float*)ws; ws += (size_t)Md * Hd * 4;           // 134 MB

    // initial h -> fp16
    {
        int n4 = Md * Kd / 4;
        cvt16<<<n4 / 256, 256, 0, stream>>>((const float4*)h, (half4v*)Hbf, n4);
    }

    for (int l = 0; l < 2; ++l) {
        const float* W   = l ? W1 : W0;
        const float* src = l ? hmid : h;
        float*       dst = l ? out  : hmid;

        wtrans<<<dim3(N3 / 32, Kd / 32), dim3(32, 32), 0, stream>>>(W, Wt);
        gemm_f16_bt<<<dim3(N3 / BN, Md / BM), 256, 0, stream>>>(Hbf, Wt, Z);
        scan_phase1<<<dim3(Hd / 256, NC, Bc), 256, 0, stream>>>(Z, cA, cB);
        scan_phase2<<<(Bc * Hd) / 256, 256, 0, stream>>>(cA, cB, cS);
        scan_phase3<<<dim3(Hd / 256, NC, Bc), 256, 0, stream>>>(
            Z, cS, src, dst, (l == 0) ? Hbf : (_Float16*)nullptr);
    }
}

// Round 2
// 1133.079 us; speedup vs baseline: 1.0691x; 1.0691x over previous
//
#include <hip/hip_runtime.h>

#define Bc 8
#define Td 4096
#define Hd 1024
#define N3 3072
#define Md (Bc*Td)      // 32768
#define Kd Hd           // 1024

#define BM 128
#define BN 128
#define BK 64
#define NC 64           // chunks along T
#define CL (Td/NC)      // 64 steps per chunk

typedef _Float16 half8 __attribute__((ext_vector_type(8)));
typedef _Float16 half4v __attribute__((ext_vector_type(4)));
typedef float floatx4 __attribute__((ext_vector_type(4)));

typedef __attribute__((address_space(3))) unsigned int lds_u32;
typedef __attribute__((address_space(1))) const unsigned int glob_u32;

__device__ __forceinline__ void async_lds16(const void* g, void* l) {
    __builtin_amdgcn_global_load_lds((glob_u32*)g, (lds_u32*)l, 16, 0, 0);
}

// ---------------- fp32 -> fp16 convert (vectorized x4) ----------------
__global__ void cvt16(const float4* __restrict__ x, half4v* __restrict__ y, int n4) {
    int i = blockIdx.x * blockDim.x + threadIdx.x;
    if (i < n4) {
        float4 v = x[i];
        half4v o;
        o[0] = (_Float16)v.x; o[1] = (_Float16)v.y;
        o[2] = (_Float16)v.z; o[3] = (_Float16)v.w;
        y[i] = o;
    }
}

// ---------------- W [K,N] fp32 -> Wt [N,K] fp16 (LDS-tiled transpose) --
__global__ void wtrans(const float* __restrict__ W, _Float16* __restrict__ Wt) {
    __shared__ float t[32][33];
    int n0 = blockIdx.x * 32, k0 = blockIdx.y * 32;
    int tx = threadIdx.x, ty = threadIdx.y;
    t[ty][tx] = W[(size_t)(k0 + ty) * N3 + n0 + tx];
    __syncthreads();
    Wt[(size_t)(n0 + ty) * Kd + k0 + tx] = (_Float16)t[tx][ty];
}

// ---------------- GEMM: C[M,N] = A[M,K] * Bt[N,K]^T, fp16 in, fp16 out -
// LDS layout XOR-swizzled: element chunk (row, c) holds global chunk
// c ^ (row & 7). Swizzle applied on the GLOBAL address of the staging
// load (per-lane), so the LDS dest stays wave-uniform-base + lane*16 as
// global_load_lds requires. Kills the 16-way ds_read_b128 bank conflict
// (row stride 128 B == 32 banks).
__global__ __launch_bounds__(256) void gemm_f16_bt(
    const _Float16* __restrict__ A,   // [M,K]
    const _Float16* __restrict__ Bt,  // [N,K]
    _Float16* __restrict__ C)         // [M,N]
{
    __shared__ _Float16 As[BM * BK];
    __shared__ _Float16 Bs[BN * BK];
    const int tid  = threadIdx.x;
    const int wave = tid >> 6;
    const int lane = tid & 63;
    const int bm = blockIdx.y * BM;
    const int bn = blockIdx.x * BN;
    const int wm = (wave >> 1) * 64;
    const int wn = (wave & 1) * 64;
    const int quad = lane >> 4;
    const int lr   = lane & 15;

    floatx4 acc[4][4];
#pragma unroll
    for (int i = 0; i < 4; ++i)
#pragma unroll
        for (int j = 0; j < 4; ++j) { floatx4 z = {0.f,0.f,0.f,0.f}; acc[i][j] = z; }

    const int e0 = wave * 2048 + lane * 8;   // element index base for staging

    for (int k0 = 0; k0 < Kd; k0 += BK) {
#pragma unroll
        for (int r = 0; r < 4; ++r) {
            int e = e0 + r * 512;
            int m = e >> 6;                   // row in tile (0..127)
            int kc = ((lane & 7) ^ (m & 7)) << 3;  // swizzled source chunk
            const _Float16* ga = A  + (size_t)(bm + m) * Kd + (k0 + kc);
            const _Float16* gb = Bt + (size_t)(bn + m) * Kd + (k0 + kc);
            char* la = (char*)As + (wave * 4 + r) * 1024;
            char* lb = (char*)Bs + (wave * 4 + r) * 1024;
            async_lds16(ga, la);
            async_lds16(gb, lb);
        }
        __syncthreads();
#pragma unroll
        for (int kk = 0; kk < BK; kk += 32) {
            half8 af[4], bf[4];
#pragma unroll
            for (int i = 0; i < 4; ++i) {
                int row = wm + i * 16 + lr;
                int ck  = (((kk >> 3) + quad) ^ (row & 7)) << 3;
                af[i] = *(const half8*)&As[row * BK + ck];
            }
#pragma unroll
            for (int j = 0; j < 4; ++j) {
                int row = wn + j * 16 + lr;
                int ck  = (((kk >> 3) + quad) ^ (row & 7)) << 3;
                bf[j] = *(const half8*)&Bs[row * BK + ck];
            }
#pragma unroll
            for (int i = 0; i < 4; ++i)
#pragma unroll
                for (int j = 0; j < 4; ++j)
                    acc[i][j] = __builtin_amdgcn_mfma_f32_16x16x32_f16(af[i], bf[j], acc[i][j], 0, 0, 0);
        }
        __syncthreads();
    }

    // epilogue: C/D layout col = lane&15, row = quad*4 + reg  [m89-verified]
#pragma unroll
    for (int i = 0; i < 4; ++i) {
#pragma unroll
        for (int j = 0; j < 4; ++j) {
            int row0 = bm + wm + i * 16 + quad * 4;
            int col  = bn + wn + j * 16 + lr;
#pragma unroll
            for (int r = 0; r < 4; ++r)
                C[(size_t)(row0 + r) * N3 + col] = (_Float16)acc[i][j][r];
        }
    }
}

// ---------------- scan phase 1: per-chunk (A, B) composition ----------
__global__ __launch_bounds__(256) void scan_phase1(
    const _Float16* __restrict__ Z, float* __restrict__ cA, float* __restrict__ cB)
{
    int ch = blockIdx.x * 256 + threadIdx.x;   // 0..1023 (gridDim.x = 4)
    int c  = blockIdx.y;
    int b  = blockIdx.z;
    int t0 = c * CL;
    float Ap = 1.0f, Bv = 0.0f;
    const _Float16* zp = Z + ((size_t)(b * Td + t0)) * N3 + ch;
#pragma unroll 4
    for (int t = 0; t < CL; ++t) {
        float hv = (float)zp[0];
        float gv = (float)zp[Hd];
        float sg = 1.0f / (1.0f + __expf(-gv));       // sigmoid(gate)
        float at = 1.0f / (1.0f + __expf(gv));        // 1 - sigmoid(gate)
        float gh = (hv >= 0.0f) ? (hv + 0.5f) : 1.0f / (1.0f + __expf(-hv));
        float bt = sg * gh;
        Ap *= at;
        Bv = fmaf(at, Bv, bt);
        zp += N3;
    }
    size_t o = ((size_t)b * NC + c) * Hd + ch;
    cA[o] = Ap; cB[o] = Bv;
}

// ---------------- scan phase 2: prefix over chunks --------------------
__global__ void scan_phase2(const float* __restrict__ cA, const float* __restrict__ cB,
                            float* __restrict__ cS)
{
    int u = blockIdx.x * 256 + threadIdx.x;    // B*H = 8192 threads
    int b = u >> 10, ch = u & 1023;
    float s = 0.0f;
    for (int c = 0; c < NC; ++c) {
        size_t o = ((size_t)b * NC + c) * Hd + ch;
        cS[o] = s;
        s = fmaf(cA[o], s, cB[o]);
    }
}

// ---------------- scan phase 3: rescan + highway gate -----------------
// hin32/hin16: exactly one non-null. hout32 (fp32) and/or hout16 (fp16).
__global__ __launch_bounds__(256) void scan_phase3(
    const _Float16* __restrict__ Z, const float* __restrict__ cS,
    const float* __restrict__ hin32, const _Float16* __restrict__ hin16,
    float* __restrict__ hout32, _Float16* __restrict__ hout16)
{
    int ch = blockIdx.x * 256 + threadIdx.x;
    int c  = blockIdx.y;
    int b  = blockIdx.z;
    int t0 = c * CL;
    float s = cS[((size_t)b * NC + c) * Hd + ch];
    const _Float16* zp = Z + ((size_t)(b * Td + t0)) * N3 + ch;
    size_t ho = ((size_t)(b * Td + t0)) * Hd + ch;
#pragma unroll 2
    for (int t = 0; t < CL; ++t) {
        float hv = (float)zp[0];
        float gv = (float)zp[Hd];
        float pv = (float)zp[2 * Hd];
        float sg = 1.0f / (1.0f + __expf(-gv));
        float at = 1.0f / (1.0f + __expf(gv));
        float gh = (hv >= 0.0f) ? (hv + 0.5f) : 1.0f / (1.0f + __expf(-hv));
        s = fmaf(at, s, sg * gh);
        float gg = 1.0f / (1.0f + __expf(-pv));
        float hi = hin32 ? hin32[ho] : (float)hin16[ho];
        float o  = fmaf(gg, s - hi, hi);
        if (hout32) hout32[ho] = o;
        if (hout16) hout16[ho] = (_Float16)o;
        zp += N3; ho += Hd;
    }
}

extern "C" void kernel_launch(void* const* d_in, const int* in_sizes, int n_in,
                              void* d_out, int out_size, void* d_ws, size_t ws_size,
                              hipStream_t stream) {
    const float* h  = (const float*)d_in[0];
    const float* W0 = (const float*)d_in[1];
    const float* W1 = (const float*)d_in[2];
    float* out = (float*)d_out;

    char* ws = (char*)d_ws;
    _Float16* Z    = (_Float16*)ws; ws += (size_t)Md * N3 * 2;     // 192 MiB
    _Float16* Hbf  = (_Float16*)ws; ws += (size_t)Md * Kd * 2;     // 64 MiB
    _Float16* Wt   = (_Float16*)ws; ws += (size_t)N3 * Kd * 2;     // 6 MiB
    float* cA   = (float*)ws; ws += (size_t)Bc * NC * Hd * 4;      // 2 MiB
    float* cB   = (float*)ws; ws += (size_t)Bc * NC * Hd * 4;
    float* cS   = (float*)ws; ws += (size_t)Bc * NC * Hd * 4;

    // initial h -> fp16
    {
        int n4 = Md * Kd / 4;
        cvt16<<<n4 / 256, 256, 0, stream>>>((const float4*)h, (half4v*)Hbf, n4);
    }

    for (int l = 0; l < 2; ++l) {
        const float* W = l ? W1 : W0;

        wtrans<<<dim3(N3 / 32, Kd / 32), dim3(32, 32), 0, stream>>>(W, Wt);
        gemm_f16_bt<<<dim3(N3 / BN, Md / BM), 256, 0, stream>>>(Hbf, Wt, Z);
        scan_phase1<<<dim3(Hd / 256, NC, Bc), 256, 0, stream>>>(Z, cA, cB);
        scan_phase2<<<(Bc * Hd) / 256, 256, 0, stream>>>(cA, cB, cS);
        if (l == 0) {
            // layer 0: hin = original h (fp32); out lives only as fp16 Hbf
            scan_phase3<<<dim3(Hd / 256, NC, Bc), 256, 0, stream>>>(
                Z, cS, h, nullptr, nullptr, Hbf);
        } else {
            // layer 1: hin = Hbf (fp16); final out fp32
            scan_phase3<<<dim3(Hd / 256, NC, Bc), 256, 0, stream>>>(
                Z, cS, nullptr, Hbf, out, nullptr);
        }
    }
}

// Round 3
// 1099.118 us; speedup vs baseline: 1.1022x; 1.0309x over previous
//
#include <hip/hip_runtime.h>

#define Bc 8
#define Td 4096
#define Hd 1024
#define N3 3072
#define Md (Bc*Td)      // 32768
#define Kd Hd           // 1024

#define BM 128
#define BN 128
#define BK 64
#define NC 64           // chunks along T
#define CL (Td/NC)      // 64 steps per chunk

typedef _Float16 half8 __attribute__((ext_vector_type(8)));
typedef _Float16 half4v __attribute__((ext_vector_type(4)));
typedef float floatx4 __attribute__((ext_vector_type(4)));

typedef __attribute__((address_space(3))) unsigned int lds_u32;
typedef __attribute__((address_space(1))) const unsigned int glob_u32;

__device__ __forceinline__ void async_lds16(const void* g, void* l) {
    __builtin_amdgcn_global_load_lds((glob_u32*)g, (lds_u32*)l, 16, 0, 0);
}

// sigmoid, single exp+rcp, no overflow
__device__ __forceinline__ float sigm(float x) {
    return 1.0f / (1.0f + __expf(-x));
}
// g(x) = x>=0 ? x+0.5 : sigmoid(x); exp(-|x|) never overflows
__device__ __forceinline__ float gfun(float x) {
    float e = __expf(-fabsf(x));
    return (x >= 0.0f) ? (x + 0.5f) : e / (1.0f + e);
}

// ---------------- fp32 -> fp16 convert (vectorized x4) ----------------
__global__ void cvt16(const float4* __restrict__ x, half4v* __restrict__ y, int n4) {
    int i = blockIdx.x * blockDim.x + threadIdx.x;
    if (i < n4) {
        float4 v = x[i];
        half4v o;
        o[0] = (_Float16)v.x; o[1] = (_Float16)v.y;
        o[2] = (_Float16)v.z; o[3] = (_Float16)v.w;
        y[i] = o;
    }
}

// ---------------- W [K,N] fp32 -> Wt [N,K] fp16 (LDS-tiled transpose) --
__global__ void wtrans(const float* __restrict__ W, _Float16* __restrict__ Wt) {
    __shared__ float t[32][33];
    int n0 = blockIdx.x * 32, k0 = blockIdx.y * 32;
    int tx = threadIdx.x, ty = threadIdx.y;
    t[ty][tx] = W[(size_t)(k0 + ty) * N3 + n0 + tx];
    __syncthreads();
    Wt[(size_t)(n0 + ty) * Kd + k0 + tx] = (_Float16)t[tx][ty];
}

// ---------------- GEMM: C[M,N] = A[M,K] * Bt[N,K]^T, fp16 in, fp16 out -
// XOR-swizzled LDS (R1: killed the 16-way ds_read_b128 conflict; conflicts=0).
__global__ __launch_bounds__(256) void gemm_f16_bt(
    const _Float16* __restrict__ A,   // [M,K]
    const _Float16* __restrict__ Bt,  // [N,K]
    _Float16* __restrict__ C)         // [M,N]
{
    __shared__ _Float16 As[BM * BK];
    __shared__ _Float16 Bs[BN * BK];
    const int tid  = threadIdx.x;
    const int wave = tid >> 6;
    const int lane = tid & 63;
    const int bm = blockIdx.y * BM;
    const int bn = blockIdx.x * BN;
    const int wm = (wave >> 1) * 64;
    const int wn = (wave & 1) * 64;
    const int quad = lane >> 4;
    const int lr   = lane & 15;

    floatx4 acc[4][4];
#pragma unroll
    for (int i = 0; i < 4; ++i)
#pragma unroll
        for (int j = 0; j < 4; ++j) { floatx4 z = {0.f,0.f,0.f,0.f}; acc[i][j] = z; }

    const int e0 = wave * 2048 + lane * 8;

    for (int k0 = 0; k0 < Kd; k0 += BK) {
#pragma unroll
        for (int r = 0; r < 4; ++r) {
            int e = e0 + r * 512;
            int m = e >> 6;                        // row in tile (0..127)
            int kc = ((lane & 7) ^ (m & 7)) << 3;  // swizzled source chunk
            const _Float16* ga = A  + (size_t)(bm + m) * Kd + (k0 + kc);
            const _Float16* gb = Bt + (size_t)(bn + m) * Kd + (k0 + kc);
            char* la = (char*)As + (wave * 4 + r) * 1024;
            char* lb = (char*)Bs + (wave * 4 + r) * 1024;
            async_lds16(ga, la);
            async_lds16(gb, lb);
        }
        __syncthreads();
#pragma unroll
        for (int kk = 0; kk < BK; kk += 32) {
            half8 af[4], bf[4];
#pragma unroll
            for (int i = 0; i < 4; ++i) {
                int row = wm + i * 16 + lr;
                int ck  = (((kk >> 3) + quad) ^ (row & 7)) << 3;
                af[i] = *(const half8*)&As[row * BK + ck];
            }
#pragma unroll
            for (int j = 0; j < 4; ++j) {
                int row = wn + j * 16 + lr;
                int ck  = (((kk >> 3) + quad) ^ (row & 7)) << 3;
                bf[j] = *(const half8*)&Bs[row * BK + ck];
            }
#pragma unroll
            for (int i = 0; i < 4; ++i)
#pragma unroll
                for (int j = 0; j < 4; ++j)
                    acc[i][j] = __builtin_amdgcn_mfma_f32_16x16x32_f16(af[i], bf[j], acc[i][j], 0, 0, 0);
        }
        __syncthreads();
    }

    // epilogue: C/D layout col = lane&15, row = quad*4 + reg  [m89-verified]
#pragma unroll
    for (int i = 0; i < 4; ++i) {
#pragma unroll
        for (int j = 0; j < 4; ++j) {
            int row0 = bm + wm + i * 16 + quad * 4;
            int col  = bn + wn + j * 16 + lr;
#pragma unroll
            for (int r = 0; r < 4; ++r)
                C[(size_t)(row0 + r) * N3 + col] = (_Float16)acc[i][j][r];
        }
    }
}

// ---------------- scan phase 1: per-chunk (A, B) composition ----------
// 4 channels/thread: half4 (8B) loads, 4 independent chains for ILP.
__global__ __launch_bounds__(256) void scan_phase1(
    const _Float16* __restrict__ Z, float* __restrict__ cA, float* __restrict__ cB)
{
    int ch = threadIdx.x * 4;                  // gridDim.x == 1, covers H=1024
    int c  = blockIdx.y;
    int b  = blockIdx.z;
    const _Float16* zp = Z + ((size_t)(b * Td + c * CL)) * N3 + ch;
    float Ap[4] = {1.f, 1.f, 1.f, 1.f};
    float Bv[4] = {0.f, 0.f, 0.f, 0.f};
#pragma unroll 4
    for (int t = 0; t < CL; ++t) {
        half4v h4 = *(const half4v*)(zp);
        half4v g4 = *(const half4v*)(zp + Hd);
#pragma unroll
        for (int i = 0; i < 4; ++i) {
            float sg = sigm((float)g4[i]);
            float at = 1.0f - sg;
            float bt = sg * gfun((float)h4[i]);
            Ap[i] *= at;
            Bv[i] = fmaf(at, Bv[i], bt);
        }
        zp += N3;
    }
    size_t o = ((size_t)b * NC + c) * Hd + ch;
    *(float4*)&cA[o] = make_float4(Ap[0], Ap[1], Ap[2], Ap[3]);
    *(float4*)&cB[o] = make_float4(Bv[0], Bv[1], Bv[2], Bv[3]);
}

// ---------------- scan phase 2: prefix over chunks (float4) -----------
__global__ void scan_phase2(const float* __restrict__ cA, const float* __restrict__ cB,
                            float* __restrict__ cS)
{
    int u = (blockIdx.x * 256 + threadIdx.x) * 4;   // B*H/4 = 2048 threads
    int b = u >> 10, ch = u & 1023;
    float4 s = make_float4(0.f, 0.f, 0.f, 0.f);
    for (int c = 0; c < NC; ++c) {
        size_t o = ((size_t)b * NC + c) * Hd + ch;
        *(float4*)&cS[o] = s;
        float4 a = *(const float4*)&cA[o];
        float4 v = *(const float4*)&cB[o];
        s.x = fmaf(a.x, s.x, v.x);
        s.y = fmaf(a.y, s.y, v.y);
        s.z = fmaf(a.z, s.z, v.z);
        s.w = fmaf(a.w, s.w, v.w);
    }
}

// ---------------- scan phase 3: rescan + highway gate -----------------
// 4 channels/thread. hin32/hin16: exactly one non-null; same for hout.
__global__ __launch_bounds__(256) void scan_phase3(
    const _Float16* __restrict__ Z, const float* __restrict__ cS,
    const float* __restrict__ hin32, const _Float16* __restrict__ hin16,
    float* __restrict__ hout32, _Float16* __restrict__ hout16)
{
    int ch = threadIdx.x * 4;                  // gridDim.x == 1
    int c  = blockIdx.y;
    int b  = blockIdx.z;
    float s[4];
    {
        float4 s4 = *(const float4*)&cS[((size_t)b * NC + c) * Hd + ch];
        s[0] = s4.x; s[1] = s4.y; s[2] = s4.z; s[3] = s4.w;
    }
    const _Float16* zp = Z + ((size_t)(b * Td + c * CL)) * N3 + ch;
    size_t ho = ((size_t)(b * Td + c * CL)) * Hd + ch;
#pragma unroll 2
    for (int t = 0; t < CL; ++t) {
        half4v h4 = *(const half4v*)(zp);
        half4v g4 = *(const half4v*)(zp + Hd);
        half4v p4 = *(const half4v*)(zp + 2 * Hd);
        float hi[4];
        if (hin32) {
            float4 v = *(const float4*)&hin32[ho];
            hi[0] = v.x; hi[1] = v.y; hi[2] = v.z; hi[3] = v.w;
        } else {
            half4v v = *(const half4v*)&hin16[ho];
#pragma unroll
            for (int i = 0; i < 4; ++i) hi[i] = (float)v[i];
        }
        float o[4];
#pragma unroll
        for (int i = 0; i < 4; ++i) {
            float sg = sigm((float)g4[i]);
            float at = 1.0f - sg;
            s[i] = fmaf(at, s[i], sg * gfun((float)h4[i]));
            float gg = sigm((float)p4[i]);
            o[i] = fmaf(gg, s[i] - hi[i], hi[i]);
        }
        if (hout32) *(float4*)&hout32[ho] = make_float4(o[0], o[1], o[2], o[3]);
        if (hout16) {
            half4v v;
#pragma unroll
            for (int i = 0; i < 4; ++i) v[i] = (_Float16)o[i];
            *(half4v*)&hout16[ho] = v;
        }
        zp += N3; ho += Hd;
    }
}

extern "C" void kernel_launch(void* const* d_in, const int* in_sizes, int n_in,
                              void* d_out, int out_size, void* d_ws, size_t ws_size,
                              hipStream_t stream) {
    const float* h  = (const float*)d_in[0];
    const float* W0 = (const float*)d_in[1];
    const float* W1 = (const float*)d_in[2];
    float* out = (float*)d_out;

    char* ws = (char*)d_ws;
    _Float16* Z    = (_Float16*)ws; ws += (size_t)Md * N3 * 2;     // 192 MiB
    _Float16* Hbf  = (_Float16*)ws; ws += (size_t)Md * Kd * 2;     // 64 MiB
    _Float16* Wt   = (_Float16*)ws; ws += (size_t)N3 * Kd * 2;     // 6 MiB
    float* cA   = (float*)ws; ws += (size_t)Bc * NC * Hd * 4;      // 2 MiB
    float* cB   = (float*)ws; ws += (size_t)Bc * NC * Hd * 4;
    float* cS   = (float*)ws; ws += (size_t)Bc * NC * Hd * 4;

    // initial h -> fp16
    {
        int n4 = Md * Kd / 4;
        cvt16<<<n4 / 256, 256, 0, stream>>>((const float4*)h, (half4v*)Hbf, n4);
    }

    for (int l = 0; l < 2; ++l) {
        const float* W = l ? W1 : W0;

        wtrans<<<dim3(N3 / 32, Kd / 32), dim3(32, 32), 0, stream>>>(W, Wt);
        gemm_f16_bt<<<dim3(N3 / BN, Md / BM), 256, 0, stream>>>(Hbf, Wt, Z);
        scan_phase1<<<dim3(1, NC, Bc), 256, 0, stream>>>(Z, cA, cB);
        scan_phase2<<<(Bc * Hd / 4) / 256, 256, 0, stream>>>(cA, cB, cS);
        if (l == 0) {
            scan_phase3<<<dim3(1, NC, Bc), 256, 0, stream>>>(
                Z, cS, h, nullptr, nullptr, Hbf);
        } else {
            scan_phase3<<<dim3(1, NC, Bc), 256, 0, stream>>>(
                Z, cS, nullptr, Hbf, out, nullptr);
        }
    }
}